// Round 4
// baseline (230.581 us; speedup 1.0000x reference)
//
#include <hip/hip_runtime.h>
#include <math.h>

// LearnableHighpass biquad, B=64, T=524288, fp32.
// Chunked-parallel IIR: pole radius ~0.888 -> 128-sample zero-state warm-up
// converges state to ~3e-7 (threshold 1.075e-1).
// R4 = R3 with native ext_vector_type(4) instead of HIP float4 so
// __builtin_nontemporal_store compiles:
//  - LT=512 (1.25x read redundancy), GV=8 full-128B-line stages
//  - nontemporal y stores (y is write-once; keep x L2/L3-resident in replays)
//  - peeled last iteration (no prefetch past chunk end, no high clamp)

typedef float f4 __attribute__((ext_vector_type(4)));

namespace {
constexpr int T_LEN = 524288;
constexpr int B_ROWS = 64;
constexpr int LT = 512;              // per-thread chunk (samples)
constexpr int WU = 128;              // warm-up samples
constexpr int CPR = T_LEN / LT;      // 1024 chunks per row
constexpr int NV = T_LEN / 4;        // f4 vectors per row
constexpr int GV = 8;                // vectors per stage (32 samples = 128 B)
constexpr int ITERS = (WU + LT) / (4 * GV);  // 20 stages
constexpr int SKIP = WU / (4 * GV);          // 4 warm-up stages (no store)
}

__global__ __launch_bounds__(256) void hp_biquad(
    const float* __restrict__ x,
    const float* __restrict__ ffreq,
    const float* __restrict__ fqv,
    const int*  __restrict__ srv,
    float* __restrict__ y)
{
    const float fsr   = (float)srv[0];
    const float w0    = 6.28318530717958647692f * ffreq[0] / fsr;
    const float sw    = sinf(w0);
    const float cw    = cosf(w0);
    const float alpha = sw / (2.0f * fqv[0]);
    const float ia0   = 1.0f / (1.0f + alpha);
    const float b0 = 0.5f * (1.0f + cw) * ia0;
    const float b1 = -(1.0f + cw) * ia0;
    const float b2 = b0;
    const float a1 = -2.0f * cw * ia0;
    const float a2 = (1.0f - alpha) * ia0;

    const int g   = blockIdx.x * blockDim.x + threadIdx.x;
    const int row = g / CPR;
    const int ci  = g % CPR;
    if (row >= B_ROWS) return;

    const f4* __restrict__ xv = (const f4*)(x + (size_t)row * T_LEN);
    f4* __restrict__ yv       = (f4*)(y + (size_t)row * T_LEN);

    const int iStart = ci * (LT / 4);
    const int i0     = iStart - WU / 4;    // negative only for ci==0

    float xm1 = 0.f, xm2 = 0.f, ym1 = 0.f, ym2 = 0.f;

    // Max index ever touched: i0 + GV*ITERS - 1 = iStart + 127 < NV always
    // (last chunk: iStart+128 == NV). Only the low side needs handling.
    auto LD = [&](int i) -> f4 {
        int j = i < 0 ? 0 : i;
        f4 v = xv[j];
        if (i < 0) v = (f4)(0.f);
        return v;
    };

    auto step = [&](float xt) -> float {
        // off-critical-path terms first; critical path = single FMA on ym1
        float t  = b0 * xt + b1 * xm1 + b2 * xm2 - a2 * ym2;
        float yt = t - a1 * ym1;
        xm2 = xm1; xm1 = xt;
        ym2 = ym1; ym1 = yt;
        return yt;
    };
    auto proc4 = [&](f4 c) -> f4 {
        f4 o;
        o.x = step(c.x); o.y = step(c.y); o.z = step(c.z); o.w = step(c.w);
        return o;
    };
    auto store_stage = [&](const f4* o, int k) {
        const int ob = i0 + GV * k;
#pragma unroll
        for (int v = 0; v < GV; ++v)
            __builtin_nontemporal_store(o[v], &yv[ob + v]);
    };

    // 1-deep software pipeline over 8-vector (128 B) stages, last iter peeled
    f4 cur[GV], nxt[GV];
#pragma unroll
    for (int v = 0; v < GV; ++v) cur[v] = LD(i0 + v);

    for (int k = 0; k < ITERS - 1; ++k) {
        const int nb = i0 + GV * (k + 1);
#pragma unroll
        for (int v = 0; v < GV; ++v) nxt[v] = LD(nb + v);

        f4 o[GV];
#pragma unroll
        for (int v = 0; v < GV; ++v) o[v] = proc4(cur[v]);

        if (k >= SKIP) store_stage(o, k);   // wave-uniform branch
#pragma unroll
        for (int v = 0; v < GV; ++v) cur[v] = nxt[v];
    }
    {   // peeled final stage: no prefetch
        f4 o[GV];
#pragma unroll
        for (int v = 0; v < GV; ++v) o[v] = proc4(cur[v]);
        store_stage(o, ITERS - 1);
    }
}

extern "C" void kernel_launch(void* const* d_in, const int* in_sizes, int n_in,
                              void* d_out, int out_size, void* d_ws, size_t ws_size,
                              hipStream_t stream) {
    const float* x  = (const float*)d_in[0];
    const float* ff = (const float*)d_in[1];
    const float* fq = (const float*)d_in[2];
    const int*   sr = (const int*)d_in[3];
    float* out = (float*)d_out;

    const int total_threads = B_ROWS * CPR;   // 65536
    const int block = 256;
    const int grid  = total_threads / block;  // 256
    hp_biquad<<<grid, block, 0, stream>>>(x, ff, fq, sr, out);
}

// Round 5
// 62.969 us; speedup vs baseline: 3.6618x; 3.6618x over previous
//
#include <hip/hip_runtime.h>
#include <math.h>

// LearnableHighpass biquad, B=64, T=524288, fp32.
// Chunked-parallel IIR: pole radius ~0.888 -> 128-sample zero-state warm-up
// converges state to ~3e-7 (threshold 1.075e-1).
// R5 = R1's LT=512 + R2's GV=8 full-128B-line stages + peeled last iter.
// NO nontemporal stores (R4: nt bypassed L2 write-combining, WRITE 371 MB,
// 3.2x slower — streaming writes need L2 write-back on gfx950).

typedef float f4 __attribute__((ext_vector_type(4)));

namespace {
constexpr int T_LEN = 524288;
constexpr int B_ROWS = 64;
constexpr int LT = 512;              // per-thread chunk (samples)
constexpr int WU = 128;              // warm-up samples
constexpr int CPR = T_LEN / LT;      // 1024 chunks per row
constexpr int NV = T_LEN / 4;        // f4 vectors per row
constexpr int GV = 8;                // vectors per stage (32 samples = 128 B)
constexpr int ITERS = (WU + LT) / (4 * GV);  // 20 stages
constexpr int SKIP = WU / (4 * GV);          // 4 warm-up stages (no store)
}

__global__ __launch_bounds__(256) void hp_biquad(
    const float* __restrict__ x,
    const float* __restrict__ ffreq,
    const float* __restrict__ fqv,
    const int*  __restrict__ srv,
    float* __restrict__ y)
{
    const float fsr   = (float)srv[0];
    const float w0    = 6.28318530717958647692f * ffreq[0] / fsr;
    const float sw    = sinf(w0);
    const float cw    = cosf(w0);
    const float alpha = sw / (2.0f * fqv[0]);
    const float ia0   = 1.0f / (1.0f + alpha);
    const float b0 = 0.5f * (1.0f + cw) * ia0;
    const float b1 = -(1.0f + cw) * ia0;
    const float b2 = b0;
    const float a1 = -2.0f * cw * ia0;
    const float a2 = (1.0f - alpha) * ia0;

    const int g   = blockIdx.x * blockDim.x + threadIdx.x;
    const int row = g / CPR;
    const int ci  = g % CPR;
    if (row >= B_ROWS) return;

    const f4* __restrict__ xv = (const f4*)(x + (size_t)row * T_LEN);
    f4* __restrict__ yv       = (f4*)(y + (size_t)row * T_LEN);

    const int iStart = ci * (LT / 4);
    const int i0     = iStart - WU / 4;    // negative only for ci==0

    float xm1 = 0.f, xm2 = 0.f, ym1 = 0.f, ym2 = 0.f;

    // Max index touched: i0 + GV*ITERS - 1 = iStart + 127 < NV always
    // (last chunk: iStart + 128 == NV). Only the low side needs handling.
    auto LD = [&](int i) -> f4 {
        int j = i < 0 ? 0 : i;
        f4 v = xv[j];
        if (i < 0) v = (f4)(0.f);
        return v;
    };

    auto step = [&](float xt) -> float {
        // off-critical-path terms first; critical path = single FMA on ym1
        float t  = b0 * xt + b1 * xm1 + b2 * xm2 - a2 * ym2;
        float yt = t - a1 * ym1;
        xm2 = xm1; xm1 = xt;
        ym2 = ym1; ym1 = yt;
        return yt;
    };
    auto proc4 = [&](f4 c) -> f4 {
        f4 o;
        o.x = step(c.x); o.y = step(c.y); o.z = step(c.z); o.w = step(c.w);
        return o;
    };
    auto store_stage = [&](const f4* o, int k) {
        const int ob = i0 + GV * k;
#pragma unroll
        for (int v = 0; v < GV; ++v) yv[ob + v] = o[v];
    };

    // 1-deep software pipeline over 8-vector (128 B) stages, last iter peeled
    f4 cur[GV], nxt[GV];
#pragma unroll
    for (int v = 0; v < GV; ++v) cur[v] = LD(i0 + v);

    for (int k = 0; k < ITERS - 1; ++k) {
        const int nb = i0 + GV * (k + 1);
#pragma unroll
        for (int v = 0; v < GV; ++v) nxt[v] = LD(nb + v);

        f4 o[GV];
#pragma unroll
        for (int v = 0; v < GV; ++v) o[v] = proc4(cur[v]);

        if (k >= SKIP) store_stage(o, k);   // wave-uniform branch
#pragma unroll
        for (int v = 0; v < GV; ++v) cur[v] = nxt[v];
    }
    {   // peeled final stage: no prefetch
        f4 o[GV];
#pragma unroll
        for (int v = 0; v < GV; ++v) o[v] = proc4(cur[v]);
        store_stage(o, ITERS - 1);
    }
}

extern "C" void kernel_launch(void* const* d_in, const int* in_sizes, int n_in,
                              void* d_out, int out_size, void* d_ws, size_t ws_size,
                              hipStream_t stream) {
    const float* x  = (const float*)d_in[0];
    const float* ff = (const float*)d_in[1];
    const float* fq = (const float*)d_in[2];
    const int*   sr = (const int*)d_in[3];
    float* out = (float*)d_out;

    const int total_threads = B_ROWS * CPR;   // 65536
    const int block = 256;
    const int grid  = total_threads / block;  // 256
    hp_biquad<<<grid, block, 0, stream>>>(x, ff, fq, sr, out);
}